// Round 3
// baseline (252.856 us; speedup 1.0000x reference)
//
#include <hip/hip_runtime.h>

// Problem constants (from reference setup_inputs):
//   spike_seq: (T=1024, B=16384, 2) fp32; w_exc: (1,2); w_inh: scalar.
// Outputs concatenated flat: spk_rec (T*B) then mem_rec (T*B), fp32.
#define T_LEN 1024
#define B_N   16384
#define NPT   2                 // neurons per thread (adjacent -> vector ld/st)
#define GSZ   (B_N / NPT)       // 8192 threads total
#define UNROLL 16               // timesteps per ping-pong phase

// One thread per TWO adjacent neurons; sequential over T (reset nonlinearity
// forbids parallel scan). 128 blocks x 64 threads = 1 wave on each of 128 CUs.
// Kernel time == per-wave chain time, so the only lever is cycles/step:
//   - packing 2 neurons/thread halves vmem ops per neuron-step (float4 load,
//     float2 stores) and amortizes the 64-bit address arithmetic (65KB row
//     strides can't fold into the 13-bit global offset field);
//   - UNROLL=16 keeps peak outstanding vmem ops ~64 (vmcnt is 6-bit/63-cap;
//     the previous version peaked at 128 outstanding -> issue serialization);
//   - plain stores (NOT nontemporal): round-2 A/B showed nt did not change
//     FETCH_SIZE at all, and L2-acked stores retire faster, which matters
//     because vmcnt retires strictly in order (load-waits chain behind
//     store-acks).
// Phase order is pinned with sched_barrier(0):
//   [load B][consume A][load A][consume B]  (ping-pong register buffers).
__global__ __launch_bounds__(64, 1) void FMFMNeuronInhib_34033320854098_kernel(
    const float* __restrict__ x,      // (T, B, 2)
    const float* __restrict__ w_exc,  // 2 elements: {0.7, 1.0}
    const float* __restrict__ w_inh,  // 1 element: -1.0
    float* __restrict__ out) {
  // No FMA contraction: must round mul/add separately to bit-match the
  // numpy reference — a 1-ulp mem difference at the threshold flips a spike.
#pragma clang fp contract(off)
  const int g = blockIdx.x * 64 + threadIdx.x;   // 0..GSZ-1, neurons 2g, 2g+1
  const float w0 = w_exc[0];
  const float w1 = w_exc[1];
  const float wi = w_inh[0];

  // x row t is B_N float2 = B_N/2 float4; thread g owns float4 index g.
  const float4* __restrict__ xp = (const float4*)x + g;
  float2* __restrict__ spk2 = (float2*)out + g;                          // row stride B_N/2 float2
  float2* __restrict__ mem2 = (float2*)(out + (size_t)T_LEN * B_N) + g;  // row stride B_N/2 float2

  float mem_a = 0.0f, inh_a = 0.0f;
  float mem_b = 0.0f, inh_b = 0.0f;

  auto neuron = [&](float x0, float x1, float& mem, float& inh) -> float {
#pragma clang fp contract(off)
    // cur_exc = x @ w_exc^T   (w1 = 1.0 -> mul is exact anyway)
    const float cur_exc = x0 * w0 + x1 * w1;
    // inh = 0.6*inh + x0
    inh = 0.6f * inh + x0;
    // cur = cur_exc + w_inh*inh   (wi = -1.0 -> exact negation)
    const float cur = cur_exc + wi * inh;
    // reset from PREVIOUS mem; (mem-1>0) == (mem>1) exactly (Sterbenz on [1,2],
    // sign preserved outside), and reset*1.0f == reset.
    const float reset = (mem > 1.0f) ? 1.0f : 0.0f;
    // mem = 0.9*mem + cur - reset, rounded per-op exactly as the reference
    mem = 0.9f * mem + cur - reset;
    return (mem > 1.0f) ? 1.0f : 0.0f;   // spk
  };

  auto step = [&](int t, float4 xv) {
#pragma clang fp contract(off)
    float2 s, m;
    s.x = neuron(xv.x, xv.y, mem_a, inh_a);
    s.y = neuron(xv.z, xv.w, mem_b, inh_b);
    m.x = mem_a;
    m.y = mem_b;
    const size_t row = (size_t)t * (B_N / 2);
    spk2[row] = s;
    mem2[row] = m;
  };

  float4 bufA[UNROLL];
  float4 bufB[UNROLL];

  // Prologue: A <- t = 0..UNROLL-1.
#pragma unroll
  for (int u = 0; u < UNROLL; ++u) bufA[u] = xp[(size_t)u * (B_N / 2)];
  __builtin_amdgcn_sched_barrier(0);

  for (int t0 = 0; t0 < T_LEN; t0 += 2 * UNROLL) {
    // Phase 1: issue B's loads (t0+UNROLL .. t0+2*UNROLL-1); always in range.
#pragma unroll
    for (int u = 0; u < UNROLL; ++u)
      bufB[u] = xp[(size_t)(t0 + UNROLL + u) * (B_N / 2)];
    __builtin_amdgcn_sched_barrier(0);

    // Phase 2: consume A (its loads are older than all outstanding stores).
#pragma unroll
    for (int u = 0; u < UNROLL; ++u) step(t0 + u, bufA[u]);
    __builtin_amdgcn_sched_barrier(0);

    // Phase 3: issue A's loads for the next iteration.
    if (t0 + 2 * UNROLL < T_LEN) {
#pragma unroll
      for (int u = 0; u < UNROLL; ++u)
        bufA[u] = xp[(size_t)(t0 + 2 * UNROLL + u) * (B_N / 2)];
    }
    __builtin_amdgcn_sched_barrier(0);

    // Phase 4: consume B.
#pragma unroll
    for (int u = 0; u < UNROLL; ++u) step(t0 + UNROLL + u, bufB[u]);
    __builtin_amdgcn_sched_barrier(0);
  }
}

extern "C" void kernel_launch(void* const* d_in, const int* in_sizes, int n_in,
                              void* d_out, int out_size, void* d_ws, size_t ws_size,
                              hipStream_t stream) {
  const float* x     = (const float*)d_in[0];  // spike_seq, T*B*2 floats
  const float* w_exc = (const float*)d_in[1];  // 2 floats
  const float* w_inh = (const float*)d_in[2];  // 1 float
  float* out = (float*)d_out;                  // spk_rec ++ mem_rec

  dim3 grid(GSZ / 64);  // 128 blocks -> 1 wave on each of 128 CUs
  dim3 block(64);
  hipLaunchKernelGGL(FMFMNeuronInhib_34033320854098_kernel, grid, block, 0, stream,
                     x, w_exc, w_inh, out);
}

// Round 4
// 230.877 us; speedup vs baseline: 1.0952x; 1.0952x over previous
//
#include <hip/hip_runtime.h>

// spike_seq: (T=1024, B=16384, 2) fp32; w_exc: (1,2)={0.7,1.0}; w_inh=-1.0.
// Outputs flat: spk_rec (T*B) then mem_rec (T*B), fp32.
#define T_LEN   1024
#define B_N     16384
#define PH      16                  // timesteps per pipeline phase
#define NPHASES (T_LEN / PH)        // 64
// 3-wave producer/consumer per block. Rounds 2-3 proved the bottleneck is
// the single-wave vmcnt domain: loads and stores retire strictly in order,
// so load-waits chain behind HBM store acks (~120-150 stall cyc/step).
// Splitting roles gives each wave its own counter domain:
//   wave1 loader:  global_load_lds (dwordx4) -> IN ring, 3 phases ahead,
//                  counted vmcnt(16) waits (never 0 mid-loop).
//   wave0 compute: pure VALU + LDS; zero vmem ops in its chain.
//   wave2 storer:  LDS -> coalesced global stores; store acks isolated.
// Raw s_barrier + manual waitcnt (NOT __syncthreads, which drains vmcnt(0)
// and would flush the loader's pipeline every phase).

__shared__ __align__(16) float2 IN_lds[4][PH][64];   // 32 KiB, 4-deep ring
__shared__ __align__(16) float2 OUT_lds[2][PH][64];  // 16 KiB, 2-deep ring

static __device__ __forceinline__ void block_barrier() {
  asm volatile("" ::: "memory");
  __builtin_amdgcn_s_barrier();
  asm volatile("" ::: "memory");
}

__global__ __launch_bounds__(192, 1) void FMFMNeuronInhib_34033320854098_kernel(
    const float* __restrict__ x,      // (T, B, 2)
    const float* __restrict__ w_exc,  // {0.7, 1.0}
    const float* __restrict__ w_inh,  // {-1.0}
    float* __restrict__ out) {
#pragma clang fp contract(off)
  const int lane = threadIdx.x & 63;
  const int wid  = threadIdx.x >> 6;     // 0=compute, 1=loader, 2=storer
  const int nb0  = blockIdx.x * 64;      // this block's first neuron

  float* __restrict__ spk_out = out;
  float* __restrict__ mem_out = out + (size_t)T_LEN * B_N;

  if (wid == 1) {
    // ---------------- loader ----------------
    // Phase q slice: rows t = q*PH .. q*PH+15, 64 float2 (512 B) per row.
    // One dwordx4 global_load_lds covers 2 rows (1024 B): lanes 0-31 row 2j,
    // lanes 32-63 row 2j+1. LDS dest is wave-uniform base + lane*16 (linear,
    // matches the [PH][64]float2 contiguous layout). Global src is per-lane.
    const int half = lane >> 5;
    const int l32  = lane & 31;
    auto issue_phase = [&](int q) {
#pragma unroll
      for (int j = 0; j < 8; ++j) {
        const int t = q * PH + 2 * j + half;
        const float* src = x + ((size_t)t * B_N + nb0) * 2 + (size_t)l32 * 4;
        __builtin_amdgcn_global_load_lds(
            (const __attribute__((address_space(1))) void*)src,
            (__attribute__((address_space(3))) void*)&IN_lds[q & 3][2 * j][0],
            16, 0, 0);
      }
    };
    issue_phase(0); issue_phase(1); issue_phase(2);   // 24 in flight
    asm volatile("s_waitcnt vmcnt(16)" ::: "memory"); // phase 0 landed
    block_barrier();
    for (int p = 0; p < NPHASES; ++p) {
      if (p + 3 < NPHASES) issue_phase(p + 3);
      // Before the barrier releasing phase p+1, its 8 loads (the oldest)
      // must have retired; keep the younger 16 (p+2, p+3) in flight.
      if (p <= NPHASES - 4)      asm volatile("s_waitcnt vmcnt(16)" ::: "memory");
      else if (p == NPHASES - 3) asm volatile("s_waitcnt vmcnt(8)"  ::: "memory");
      else                       asm volatile("s_waitcnt vmcnt(0)"  ::: "memory");
      block_barrier();
    }
  } else if (wid == 0) {
    // ---------------- compute ----------------
    const float w0 = w_exc[0];
    const float w1 = w_exc[1];
    const float wi = w_inh[0];
    float mem = 0.0f, inh = 0.0f;
    block_barrier();                                  // prologue barrier
    for (int p = 0; p < NPHASES; ++p) {
      float2 xv[PH];
#pragma unroll
      for (int u = 0; u < PH; ++u) xv[u] = IN_lds[p & 3][u][lane];
#pragma unroll
      for (int u = 0; u < PH; ++u) {
        const float x0 = xv[u].x;
        const float x1 = xv[u].y;
        // Exact reference op order; no FMA contraction (1-ulp flips a spike).
        const float cur_exc = x0 * w0 + x1 * w1;      // x @ w_exc^T
        inh = 0.6f * inh + x0;                        // inh decay + feed
        const float cur = cur_exc + wi * inh;         // wi = -1.0 exact
        // (mem-1>0) == (mem>1): Sterbenz-exact on [0.5,2], sign-safe outside.
        const float reset = (mem > 1.0f) ? 1.0f : 0.0f;
        mem = 0.9f * mem + cur - reset;               // reset*1.0f == reset
        const float spk = (mem > 1.0f) ? 1.0f : 0.0f;
        OUT_lds[p & 1][u][lane] = make_float2(spk, mem);
      }
      asm volatile("s_waitcnt lgkmcnt(0)" ::: "memory"); // writes visible
      block_barrier();
    }
  } else {
    // ---------------- storer ----------------
    block_barrier();                                  // prologue barrier
    for (int p = 0; p < NPHASES; ++p) {
      if (p >= 1) {
        const int tb = (p - 1) * PH;
#pragma unroll
        for (int u = 0; u < PH; ++u) {
          const float2 v = OUT_lds[(p - 1) & 1][u][lane];
          const size_t idx = (size_t)(tb + u) * B_N + nb0 + lane;
          spk_out[idx] = v.x;   // 4B/lane, 256B contiguous per row
          mem_out[idx] = v.y;
        }
        // ds_reads must retire before compute rewrites this OUT buffer next
        // phase; global stores need no wait (own vmcnt domain, fire & forget).
        asm volatile("s_waitcnt lgkmcnt(0)" ::: "memory");
      }
      block_barrier();
    }
    // Epilogue: last phase's output (no barrier needed; final in-loop
    // barrier ordered compute's writes before this).
    const int tb = (NPHASES - 1) * PH;
#pragma unroll
    for (int u = 0; u < PH; ++u) {
      const float2 v = OUT_lds[(NPHASES - 1) & 1][u][lane];
      const size_t idx = (size_t)(tb + u) * B_N + nb0 + lane;
      spk_out[idx] = v.x;
      mem_out[idx] = v.y;
    }
  }
}

extern "C" void kernel_launch(void* const* d_in, const int* in_sizes, int n_in,
                              void* d_out, int out_size, void* d_ws, size_t ws_size,
                              hipStream_t stream) {
  const float* x     = (const float*)d_in[0];  // spike_seq, T*B*2 floats
  const float* w_exc = (const float*)d_in[1];  // 2 floats
  const float* w_inh = (const float*)d_in[2];  // 1 float
  float* out = (float*)d_out;                  // spk_rec ++ mem_rec

  dim3 grid(B_N / 64);   // 256 blocks -> 1 block (3 waves) per CU
  dim3 block(192);       // wave0 compute, wave1 loader, wave2 storer
  hipLaunchKernelGGL(FMFMNeuronInhib_34033320854098_kernel, grid, block, 0, stream,
                     x, w_exc, w_inh, out);
}